// Round 3
// 411.016 us; speedup vs baseline: 1.1761x; 1.1761x over previous
//
#include <hip/hip_runtime.h>

typedef __bf16 bf16_t;
typedef __bf16 bf16x4 __attribute__((ext_vector_type(4)));
typedef __bf16 bf16x8 __attribute__((ext_vector_type(8)));
typedef float floatx4 __attribute__((ext_vector_type(4)));

#define B_    128
#define H_    14
#define HW_   196
#define C_    768
#define NH_   12
#define HD_   64
#define M_    25088
#define NQKV_ 2304
#define KDIM_ 768
#define BK_   64    // GEMM K-tile
#define VPAD_ 208   // v^T global row length (16B-aligned)
#define RSTR  72    // rT staging stride (bf16)
#define QSTR  104   // q'/k' augmented row stride in bf16 (208B = 13x16B, odd 16B count -> bank spread)
#define PSTR  232   // pb LDS row stride in bf16

// ---------------------------------------------------------------- async 16B global->LDS
__device__ __forceinline__ void async_cp16(const void* g, void* l) {
    __builtin_amdgcn_global_load_lds((const __attribute__((address_space(1))) void*)g,
                                     (__attribute__((address_space(3))) void*)l, 16, 0, 0);
}

// ---------------------------------------------------------------- cast x -> bf16
__global__ __launch_bounds__(256) void cast_x_kernel(const float* __restrict__ in,
                                                     bf16_t* __restrict__ out) {
    size_t i = ((size_t)blockIdx.x * 256 + threadIdx.x) * 8;
    float4 a = *(const float4*)(in + i);
    float4 b = *(const float4*)(in + i + 4);
    bf16x8 v;
    v[0] = (bf16_t)a.x; v[1] = (bf16_t)a.y; v[2] = (bf16_t)a.z; v[3] = (bf16_t)a.w;
    v[4] = (bf16_t)b.x; v[5] = (bf16_t)b.y; v[6] = (bf16_t)b.z; v[7] = (bf16_t)b.w;
    *(bf16x8*)(out + i) = v;
}

// ---------------------------------------------------------------- zero v^T padding cols [196,208)
__global__ __launch_bounds__(256) void zero_vpad_kernel(bf16_t* __restrict__ vtb) {
    int row = blockIdx.x * 256 + threadIdx.x;   // B_*NH_*HD_ = 98304 rows
    if (row < B_ * NH_ * HD_) {
        bf16_t* p = vtb + (size_t)row * VPAD_ + HW_;
        #pragma unroll
        for (int i = 0; i < 12; i++) p[i] = (bf16_t)0.f;
    }
}

// ------------------------------------------- transpose + cast weight (rows x cols) -> (cols x rows)
__global__ __launch_bounds__(256) void transpose_cast_kernel(const float* __restrict__ in,
                                                             bf16_t* __restrict__ out,
                                                             int rows, int cols) {
    __shared__ float tile[32][33];
    int c0 = blockIdx.x * 32, r0 = blockIdx.y * 32;
    for (int i = threadIdx.y; i < 32; i += 8) {
        int r = r0 + i, c = c0 + threadIdx.x;
        if (r < rows && c < cols) tile[i][threadIdx.x] = in[(size_t)r * cols + c];
    }
    __syncthreads();
    for (int i = threadIdx.y; i < 32; i += 8) {
        int orow = c0 + i;            // output row = input col
        int oc   = r0 + threadIdx.x;  // output col = input row
        if (orow < cols && oc < rows)
            out[(size_t)orow * rows + oc] = (bf16_t)tile[threadIdx.x][i];
    }
}

// ---------------------------------------------------------------- shared GEMM core
__device__ __forceinline__ void gemm128_compute(const bf16_t* __restrict__ A,
                                                const bf16_t* __restrict__ Bt,
                                                int m0, int n0,
                                                floatx4 acc[4][4],
                                                bf16_t (*As)[BK_], bf16_t (*Bs)[BK_]) {
    const int tid  = threadIdx.x;
    const int lane = tid & 63, wave = tid >> 6;
    const int wm = (wave & 1) << 6, wn = (wave >> 1) << 6;
    const int lrow = lane & 15, quad = lane >> 4;

    #pragma unroll
    for (int i = 0; i < 4; i++)
        #pragma unroll
        for (int j = 0; j < 4; j++) acc[i][j] = (floatx4){0.f, 0.f, 0.f, 0.f};

    const int sr = tid >> 3;        // staging base row 0..31 (+ i*32)
    const int cc = tid & 7;         // LDS column chunk (16B units)

    for (int k0 = 0; k0 < KDIM_; k0 += BK_) {
        __syncthreads();
        #pragma unroll
        for (int i = 0; i < 4; i++) {
            int row  = sr + i * 32;
            int scol = ((cc ^ (row & 7)) * 8);      // swizzled source k-chunk
            async_cp16(A  + (size_t)(m0 + row) * KDIM_ + k0 + scol, &As[row][cc * 8]);
            async_cp16(Bt + (size_t)(n0 + row) * KDIM_ + k0 + scol, &Bs[row][cc * 8]);
        }
        __syncthreads();

        #pragma unroll
        for (int kh = 0; kh < 2; kh++) {
            bf16x8 af[4], bfr[4];
            #pragma unroll
            for (int i = 0; i < 4; i++) {
                int rw = wm + i * 16 + lrow;
                af[i] = *(const bf16x8*)&As[rw][((kh * 4 + quad) ^ (rw & 7)) * 8];
            }
            #pragma unroll
            for (int j = 0; j < 4; j++) {
                int rw = wn + j * 16 + lrow;
                bfr[j] = *(const bf16x8*)&Bs[rw][((kh * 4 + quad) ^ (rw & 7)) * 8];
            }
            #pragma unroll
            for (int i = 0; i < 4; i++)
                #pragma unroll
                for (int j = 0; j < 4; j++)
                    acc[i][j] = __builtin_amdgcn_mfma_f32_16x16x32_bf16(af[i], bfr[j], acc[i][j], 0, 0, 0);
        }
    }
}

// ---------------------------------------------------------------- QKV GEMM + scatter epilogue
// q written pre-scaled by 0.125 (softmax scale folded in).
__global__ __launch_bounds__(256) void qkv_gemm_kernel(const bf16_t* __restrict__ A,
                                                       const bf16_t* __restrict__ Bt,
                                                       const float* __restrict__ bias,
                                                       bf16_t* __restrict__ qb,
                                                       bf16_t* __restrict__ kb,
                                                       bf16_t* __restrict__ vtb) {
    __shared__ __align__(16) char smem[128 * 136 * 2];   // As|Bs union Cs[128][136]
    bf16_t (*As)[BK_] = (bf16_t(*)[BK_])smem;
    bf16_t (*Bs)[BK_] = (bf16_t(*)[BK_])(smem + 128 * BK_ * 2);
    bf16_t (*Cs)[136] = (bf16_t(*)[136])smem;

    const int lin = blockIdx.x;
    const int g = lin / 72, r = lin - g * 72;
    const int m0 = (g * 4 + (r & 3)) * 128;
    const int n0 = (r >> 2) * 128;
    floatx4 acc[4][4];
    gemm128_compute(A, Bt, m0, n0, acc, As, Bs);

    const int tid = threadIdx.x;
    const int lane = tid & 63, wave = tid >> 6;
    const int wm = (wave & 1) << 6, wn = (wave >> 1) << 6;
    const int lrow = lane & 15, quad = lane >> 4;
    const int sel = n0 / C_;                     // block-uniform: 0=q 1=k 2=v

    if (sel == 2) {
        #pragma unroll
        for (int j = 0; j < 4; j++) {
            int n = n0 + wn + j * 16 + lrow;
            float bv = bias[n];
            int nc = n - 2 * C_;
            int nh = nc >> 6, hd = nc & 63;
            #pragma unroll
            for (int i = 0; i < 4; i++) {
                int m = m0 + wm + i * 16 + quad * 4;
                int b = m / HW_, t = m - b * HW_;
                int head = b * NH_ + nh;
                ushort4 pk;
                bf16_t h;
                h = (bf16_t)(acc[i][j][0] + bv); pk.x = __builtin_bit_cast(unsigned short, h);
                h = (bf16_t)(acc[i][j][1] + bv); pk.y = __builtin_bit_cast(unsigned short, h);
                h = (bf16_t)(acc[i][j][2] + bv); pk.z = __builtin_bit_cast(unsigned short, h);
                h = (bf16_t)(acc[i][j][3] + bv); pk.w = __builtin_bit_cast(unsigned short, h);
                *(ushort4*)(vtb + ((size_t)head * HD_ + hd) * VPAD_ + t) = pk;
            }
        }
    } else {
        const float sc = (sel == 0) ? 0.125f : 1.0f;   // fold softmax scale into q
        __syncthreads();   // As/Bs reads complete before Cs overwrite
        #pragma unroll
        for (int j = 0; j < 4; j++) {
            int n = n0 + wn + j * 16 + lrow;
            float bv = bias[n];
            #pragma unroll
            for (int i = 0; i < 4; i++)
                #pragma unroll
                for (int rr = 0; rr < 4; rr++)
                    Cs[wm + i * 16 + quad * 4 + rr][wn + j * 16 + lrow] =
                        (bf16_t)((acc[i][j][rr] + bv) * sc);
        }
        __syncthreads();
        bf16_t* dst = sel ? kb : qb;
        const int n0s = n0 - sel * C_;
        #pragma unroll
        for (int u = 0; u < 8; u++) {
            int idx = tid + u * 256;
            int rr = idx >> 4, c = idx & 15;
            int m = m0 + rr;
            int b = m / HW_, t = m - b * HW_;
            int ncol = n0s + c * 8;
            int nh = ncol >> 6, hd = ncol & 63;
            *(uint4*)(dst + (((size_t)(b * NH_ + nh)) * HW_ + t) * HD_ + hd) =
                *(const uint4*)&Cs[rr][c * 8];
        }
    }
}

// ---------------------------------------------------------------- proj GEMM + bias -> fp32 out
__global__ __launch_bounds__(256) void proj_gemm_kernel(const bf16_t* __restrict__ A,
                                                        const bf16_t* __restrict__ Bt,
                                                        const float* __restrict__ bias,
                                                        float* __restrict__ out) {
    __shared__ __align__(16) bf16_t As[128][BK_];
    __shared__ __align__(16) bf16_t Bs[128][BK_];
    const int lin = blockIdx.x;
    const int g = lin / 24, r = lin - g * 24;
    const int m0 = (g * 4 + (r & 3)) * 128;
    const int n0 = (r >> 2) * 128;
    floatx4 acc[4][4];
    gemm128_compute(A, Bt, m0, n0, acc, As, Bs);

    const int lane = threadIdx.x & 63, wave = threadIdx.x >> 6;
    const int wm = (wave & 1) << 6, wn = (wave >> 1) << 6;
    const int lrow = lane & 15, quad = lane >> 4;
    #pragma unroll
    for (int j = 0; j < 4; j++) {
        int n = n0 + wn + j * 16 + lrow;
        float bv = bias[n];
        #pragma unroll
        for (int i = 0; i < 4; i++) {
            #pragma unroll
            for (int rr = 0; rr < 4; rr++) {
                int m = m0 + wm + i * 16 + quad * 4 + rr;
                out[(size_t)m * C_ + n] = acc[i][j][rr] + bv;
            }
        }
    }
}

// ---------------------------------------------------------------- fused attention
// One block per head; k' (augmented), rel tables staged ONCE; v^T held in registers
// (fragment pattern is qt-invariant); loop over the 7 q-tiles of 32 rows.
// Augmented-K: q' = [0.125q | QRh gather | QRw gather | 0] (96 cols),
// k' = [k | onehot14(kh) | onehot14(kw) | 0]; S = q'.k' in 3 MFMA k-steps.
// PV computes O^T (A=v^T regs, B=P) so output stores are packed ushort4.
__global__ __launch_bounds__(256, 2) void attn_kernel(const bf16_t* __restrict__ qb,
                                                      const bf16_t* __restrict__ kb,
                                                      const bf16_t* __restrict__ vtb,
                                                      const float* __restrict__ rph,
                                                      const float* __restrict__ rpw,
                                                      bf16_t* __restrict__ aout) {
    const int head = blockIdx.x;
    const int bb = head / NH_, nh = head - bb * NH_;
    const int tid = threadIdx.x;
    const int lane = tid & 63, wave = tid >> 6;
    const int lrow = lane & 15, quad = lane >> 4;

    __shared__ __align__(16) bf16_t qs[32][QSTR];       //  6,656 B (q', per round)
    __shared__ __align__(16) bf16_t ks[208][QSTR];      // 43,264 B (k', persistent)
    __shared__ __align__(16) bf16_t pb[32][PSTR];       // 14,848 B (P, per round)
    __shared__ __align__(16) bf16_t rT[64][RSTR];       //  9,216 B (rel tables, persistent)
    __shared__ bf16_t QRh[32][34];                      //  2,176 B each (per round)
    __shared__ bf16_t QRw[32][34];
    __shared__ float pmax[2][32], psum[2][32];          //    512 B
    // total 78,848 B -> 2 blocks/CU

    bf16x8 z;
    #pragma unroll
    for (int e = 0; e < 8; e++) z[e] = (bf16_t)0.f;

    // ---- once-per-head: stage rel tables + k' data + zero aug cols
    #pragma unroll
    for (int t2 = 0; t2 < 2; t2++) {
        int u = tid * 2 + t2;              // 0..511
        int which = u >> 8, rem = u & 255;
        int l = rem >> 3, c = (rem & 7) * 8;
        bf16x8 v = z;
        if (l < 27) {
            const float* src = (which ? rpw : rph) + (size_t)l * HD_ + c;
            float4 a = *(const float4*)src;
            float4 b = *(const float4*)(src + 4);
            v[0] = (bf16_t)a.x; v[1] = (bf16_t)a.y; v[2] = (bf16_t)a.z; v[3] = (bf16_t)a.w;
            v[4] = (bf16_t)b.x; v[5] = (bf16_t)b.y; v[6] = (bf16_t)b.z; v[7] = (bf16_t)b.w;
        }
        *(bf16x8*)&rT[which * 32 + l][c] = v;
    }
    for (int v8 = tid; v8 < 208 * 8; v8 += 256) {          // k data cols 0..63
        int row = v8 >> 3, col = (v8 & 7) * 8;
        *(bf16x8*)&ks[row][col] =
            (row < HW_) ? *(const bf16x8*)(kb + ((size_t)head * HW_ + row) * HD_ + col) : z;
    }
    for (int u = tid; u < 208 * 5; u += 256) {             // zero cols 64..103
        int row = u / 5, c = u - row * 5;
        *(bf16x8*)&ks[row][64 + c * 8] = z;
    }

    // ---- v^T fragments into registers (qt-invariant; L2/L3 hits, hidden under staging)
    bf16x8 vfr[2][7];
    #pragma unroll
    for (int jj = 0; jj < 2; jj++) {
        int hdt = (wave >> 1) * 2 + jj;
        #pragma unroll
        for (int kk = 0; kk < 7; kk++) {
            int col = kk * 32 + quad * 8;
            bool ok = (col < VPAD_);
            bf16x8 t = *(const bf16x8*)(vtb + ((size_t)head * HD_ + hdt * 16 + lrow) * VPAD_
                                        + (ok ? col : 0));
            vfr[jj][kk] = ok ? t : z;
        }
    }

    // ---- q prefetch for round 0
    const int qrow_st = tid >> 3, qcol_st = (tid & 7) * 8;
    bf16x8 qreg = *(const bf16x8*)(qb + ((size_t)head * HW_ + qrow_st) * HD_ + qcol_st);

    __syncthreads();                                        // zeros visible before one-hots
    if (tid < HW_) {                                        // one-hots (valid keys only)
        int kh = tid / 14, kw = tid - kh * 14;
        ks[tid][64 + kh] = (bf16_t)1.0f;
        ks[tid][78 + kw] = (bf16_t)1.0f;
    }
    if (tid < 96) {                                         // zero pb pad cols 208..231 (once)
        int row = tid / 3, col = 208 + (tid % 3) * 8;
        *(bf16x8*)&pb[row][col] = z;
    }

    const int wh = wave >> 1, mi = wave & 1;
    const int qit = wave & 1;

    for (int qt = 0; qt < 7; qt++) {
        const int q0 = qt * 32;

        // ---- commit staged q (cols 0..63)
        *(bf16x8*)&qs[qrow_st][qcol_st] = qreg;
        __syncthreads();                                    // B_q: qs (+ round0: ks', rT) ready

        // ---- QR tables via MFMA (8 tasks over 4 waves); x8 compensates q pre-scale
        #pragma unroll
        for (int t2 = 0; t2 < 2; t2++) {
            int tsk = wave * 2 + t2;
            int which = tsk >> 2, mi2 = (tsk >> 1) & 1, ni = tsk & 1;
            floatx4 a4 = (floatx4){0.f, 0.f, 0.f, 0.f};
            #pragma unroll
            for (int kk = 0; kk < 2; kk++) {
                bf16x8 af  = *(const bf16x8*)&qs[mi2 * 16 + lrow][kk * 32 + quad * 8];
                bf16x8 bf8 = *(const bf16x8*)&rT[which * 32 + ni * 16 + lrow][kk * 32 + quad * 8];
                a4 = __builtin_amdgcn_mfma_f32_16x16x32_bf16(af, bf8, a4, 0, 0, 0);
            }
            int l = ni * 16 + lrow;
            if (l < 27) {
                bf16_t (*QR)[34] = which ? QRw : QRh;
                #pragma unroll
                for (int rr = 0; rr < 4; rr++) QR[mi2 * 16 + quad * 4 + rr][l] = (bf16_t)(a4[rr] * 8.f);
            }
        }
        __syncthreads();                                    // B_qr: QR ready

        // ---- build q' gather cols 64..95 (packed 4-col write per thread)
        {
            int row = tid >> 3;
            int kk4 = (tid & 7) * 4;
            int t = q0 + row;
            int h = t / 14, w = t - h * 14;
            bf16x4 pk;
            #pragma unroll
            for (int s = 0; s < 4; s++) {
                int kk = kk4 + s;
                bf16_t val = (bf16_t)0.f;
                if (kk < 14)      val = QRh[row][h - kk + 13];
                else if (kk < 28) val = QRw[row][w - (kk - 14) + 13];
                pk[s] = val;
            }
            *(bf16x4*)&qs[row][64 + kk4] = pk;
        }
        __syncthreads();                                    // B_qp: q' ready

        // ---- S = q'.k' fragments in registers (wave wh covers jt = 2t+wh); fully unrolled
        float sv[7][4];
        float m4[4] = {-1e30f, -1e30f, -1e30f, -1e30f};
        #pragma unroll
        for (int t = 0; t < 7; t++) {
            int jt = 2 * t + wh;
            if (jt < 13) {
                floatx4 a4 = (floatx4){0.f, 0.f, 0.f, 0.f};
                #pragma unroll
                for (int kk = 0; kk < 3; kk++) {
                    bf16x8 af  = *(const bf16x8*)&qs[mi * 16 + lrow][kk * 32 + quad * 8];
                    bf16x8 bf8 = *(const bf16x8*)&ks[jt * 16 + lrow][kk * 32 + quad * 8];
                    a4 = __builtin_amdgcn_mfma_f32_16x16x32_bf16(af, bf8, a4, 0, 0, 0);
                }
                int n = jt * 16 + lrow;
                bool valid = (n < HW_);
                #pragma unroll
                for (int rr = 0; rr < 4; rr++) {
                    float s = valid ? a4[rr] : -1e30f;
                    sv[t][rr] = s;
                    m4[rr] = fmaxf(m4[rr], s);
                }
            }
        }
        #pragma unroll
        for (int off = 1; off < 16; off <<= 1)
            #pragma unroll
            for (int rr = 0; rr < 4; rr++) m4[rr] = fmaxf(m4[rr], __shfl_xor(m4[rr], off));
        if (lrow == 0)
            #pragma unroll
            for (int rr = 0; rr < 4; rr++) pmax[wh][mi * 16 + quad * 4 + rr] = m4[rr];
        __syncthreads();                                    // B_pm: pmax ready

        // ---- exp -> unnormalized P in pb; per-row partial sums
        float mxr[4], s4[4] = {0.f, 0.f, 0.f, 0.f};
        #pragma unroll
        for (int rr = 0; rr < 4; rr++) {
            int qi = mi * 16 + quad * 4 + rr;
            mxr[rr] = fmaxf(pmax[0][qi], pmax[1][qi]);
        }
        #pragma unroll
        for (int t = 0; t < 7; t++) {
            int jt = 2 * t + wh;
            if (jt < 13) {
                int n = jt * 16 + lrow;
                #pragma unroll
                for (int rr = 0; rr < 4; rr++) {
                    float e = __expf(sv[t][rr] - mxr[rr]);
                    s4[rr] += e;
                    pb[mi * 16 + quad * 4 + rr][n] = (bf16_t)e;
                }
            }
        }
        #pragma unroll
        for (int off = 1; off < 16; off <<= 1)
            #pragma unroll
            for (int rr = 0; rr < 4; rr++) s4[rr] += __shfl_xor(s4[rr], off);
        if (lrow == 0)
            #pragma unroll
            for (int rr = 0; rr < 4; rr++) psum[wh][mi * 16 + quad * 4 + rr] = s4[rr];
        __syncthreads();                                    // B_ps: pb, psum ready

        // ---- O^T = V^T @ P  (A = vfr regs, B = pb) -> packed stores
        const int qrow = qit * 16 + lrow;
        const float inv = 1.f / (psum[0][qrow] + psum[1][qrow]);
        const int t_out = q0 + qrow;

        // prefetch next round's q during PV
        if (qt < 6) {
            int t = q0 + 32 + qrow_st;
            qreg = (t < HW_) ? *(const bf16x8*)(qb + ((size_t)head * HW_ + t) * HD_ + qcol_st) : z;
        }

        #pragma unroll
        for (int jj = 0; jj < 2; jj++) {
            int hdt = (wave >> 1) * 2 + jj;
            floatx4 a4 = (floatx4){0.f, 0.f, 0.f, 0.f};
            #pragma unroll
            for (int kk = 0; kk < 7; kk++) {
                bf16x8 bf8 = *(const bf16x8*)&pb[qit * 16 + lrow][kk * 32 + quad * 8];
                a4 = __builtin_amdgcn_mfma_f32_16x16x32_bf16(vfr[jj][kk], bf8, a4, 0, 0, 0);
            }
            if (t_out < HW_) {
                int col = nh * HD_ + hdt * 16 + quad * 4;
                ushort4 pk;
                bf16_t hv;
                hv = (bf16_t)(a4[0] * inv); pk.x = __builtin_bit_cast(unsigned short, hv);
                hv = (bf16_t)(a4[1] * inv); pk.y = __builtin_bit_cast(unsigned short, hv);
                hv = (bf16_t)(a4[2] * inv); pk.z = __builtin_bit_cast(unsigned short, hv);
                hv = (bf16_t)(a4[3] * inv); pk.w = __builtin_bit_cast(unsigned short, hv);
                *(ushort4*)(aout + ((size_t)bb * HW_ + t_out) * C_ + col) = pk;
            }
        }
    }
}

// ---------------------------------------------------------------- launcher
extern "C" void kernel_launch(void* const* d_in, const int* in_sizes, int n_in,
                              void* d_out, int out_size, void* d_ws, size_t ws_size,
                              hipStream_t stream) {
    const float* hs    = (const float*)d_in[0];
    const float* wqkv  = (const float*)d_in[1];
    const float* bqkv  = (const float*)d_in[2];
    const float* rph   = (const float*)d_in[3];
    const float* rpw   = (const float*)d_in[4];
    const float* wproj = (const float*)d_in[5];
    const float* bproj = (const float*)d_in[6];
    float* out = (float*)d_out;

    char* ws = (char*)d_ws;
    bf16_t* x_bf   = (bf16_t*)(ws + 0);          // 38,535,168 B; reused as aout
    bf16_t* aout   = x_bf;
    bf16_t* wqkvT  = (bf16_t*)(ws + 38535168);
    bf16_t* wprojT = (bf16_t*)(ws + 42074112);
    bf16_t* qb     = (bf16_t*)(ws + 43253760);
    bf16_t* kb     = (bf16_t*)(ws + 81788928);
    bf16_t* vtb    = (bf16_t*)(ws + 120324096);  // total 161,218,560

    cast_x_kernel<<<9408, 256, 0, stream>>>(hs, x_bf);
    zero_vpad_kernel<<<384, 256, 0, stream>>>(vtb);
    transpose_cast_kernel<<<dim3(72, 24), dim3(32, 8), 0, stream>>>(wqkv, wqkvT, 768, 2304);
    transpose_cast_kernel<<<dim3(24, 24), dim3(32, 8), 0, stream>>>(wproj, wprojT, 768, 768);
    qkv_gemm_kernel<<<3528, 256, 0, stream>>>(x_bf, wqkvT, bqkv, qb, kb, vtb);
    attn_kernel<<<B_ * NH_, 256, 0, stream>>>(qb, kb, vtb, rph, rpw, aout);
    proj_gemm_kernel<<<1176, 256, 0, stream>>>(aout, wprojT, bproj, out);
}